// Round 14
// baseline (109.846 us; speedup 1.0000x reference)
//
#include <hip/hip_runtime.h>

#define N 8192
#define D 128
#define MARGIN 0.5f
#define FLT_BIG 3.402823466e+38f
// EXACTLY 1024 blocks = one full residency round at 4 blocks/CU x 256 CU.
// T in [0,32): diagonal block for 256-square bj=T (triangular js, 18 steps/wave).
// T in [32,1024): off-diagonal 128x256 blocks, bi in [0,2bj), bj in [1,32):
// offset(bj) = bj*(bj-1), count 992. 32+992 = 1024.
#define NBLK 1024

typedef __bf16 bf16x8 __attribute__((ext_vector_type(8)));
typedef float f32x4 __attribute__((ext_vector_type(4)));
typedef unsigned short u16x8 __attribute__((ext_vector_type(8)));

__device__ __forceinline__ unsigned short f2bf_rne(float f) {
  unsigned u = __float_as_uint(f);
  u += 0x7FFFu + ((u >> 16) & 1u);  // round-to-nearest-even (inputs finite)
  return (unsigned short)(u >> 16);
}

// order-preserving float<->uint keys (R1/R9-verified)
__device__ __forceinline__ unsigned fkey(float f) {
  unsigned u = __float_as_uint(f);
  return ((int)u < 0) ? ~u : (u | 0x80000000u);
}
__device__ __forceinline__ float fkey_inv(unsigned k) {
  unsigned u = ((int)k < 0) ? (k & 0x7FFFFFFFu) : ~k;
  return __uint_as_float(u);
}

// xb layout: MFMA-fragment-major. frag[tile][k][lane][8] ushorts, where
// tile = row>>4, lane = quad*16 + (row&15), chunk (4k+quad) = row bytes
// [k*64 + quad*16 .. +16). A and B fragments of the Gram matmul share this
// exact formula, so every fragment load is base + lane*16B (fully coalesced).
#define FRAG_OFF(tile, k, lane) ((size_t)(tile) * 2048 + (size_t)(k) * 512 + (size_t)(lane) * 8)

// ---------------- K1: fp32->bf16 fragment-swizzle + row norms + init ----------
// grid 512 x 256: thread = (row, chunk c): 16 rows/block, 16 chunks/row.
__global__ void k_prep(const float* __restrict__ x, const int* __restrict__ lab,
                       unsigned short* __restrict__ xb, float* __restrict__ sq,
                       unsigned* __restrict__ posw, unsigned* __restrict__ negw,
                       unsigned* __restrict__ hist, float* __restrict__ acc,
                       unsigned* __restrict__ ticket) {
  const int t = threadIdx.x;
  const int row = blockIdx.x * 16 + (t >> 4);
  const int c = t & 15;
  const float4 v0 = ((const float4*)x)[row * 32 + c * 2];
  const float4 v1 = ((const float4*)x)[row * 32 + c * 2 + 1];
  u16x8 o;
  o[0] = f2bf_rne(v0.x); o[1] = f2bf_rne(v0.y);
  o[2] = f2bf_rne(v0.z); o[3] = f2bf_rne(v0.w);
  o[4] = f2bf_rne(v1.x); o[5] = f2bf_rne(v1.y);
  o[6] = f2bf_rne(v1.z); o[7] = f2bf_rne(v1.w);
  // chunk c -> k = c>>2, quad = c&3; lane = quad*16 + (row&15)
  *(u16x8*)(xb + FRAG_OFF(row >> 4, c >> 2, ((c & 3) * 16) + (row & 15))) = o;
  float s = v0.x * v0.x + v0.y * v0.y + v0.z * v0.z + v0.w * v0.w +
            v1.x * v1.x + v1.y * v1.y + v1.z * v1.z + v1.w * v1.w;
#pragma unroll
  for (int off = 1; off < 16; off <<= 1) s += __shfl_xor(s, off, 64);
  if (c == 0) {
    sq[row] = s;
    posw[row] = 0u;           // max(d2) accumulator
    negw[row] = 0x7F800000u;  // min(d2) accumulator = +inf
  }

  if (blockIdx.x == 0) {  // label histogram
    __shared__ unsigned h[8];
    if (t < 8) h[t] = 0u;
    __syncthreads();
    unsigned long long cA = 0ull, cB = 0ull;  // 4x16-bit packed counters each
#pragma unroll
    for (int it = 0; it < 32; ++it) {
      const int l = lab[t + it * 256] & 7;
      if (l < 4) cA += 1ull << (l * 16);
      else       cB += 1ull << ((l - 4) * 16);
    }
#pragma unroll
    for (int off = 1; off < 64; off <<= 1) {
      cA += __shfl_xor(cA, off, 64);
      cB += __shfl_xor(cB, off, 64);
    }
    if ((t & 63) == 0) {
#pragma unroll
      for (int q = 0; q < 4; ++q) {
        atomicAdd(&h[q],     (unsigned)((cA >> (q * 16)) & 0xFFFFu));
        atomicAdd(&h[4 + q], (unsigned)((cB >> (q * 16)) & 0xFFFFu));
      }
    }
    __syncthreads();
    if (t < 8) hist[t] = h[t];
    if (t == 0) { acc[0] = 0.f; acc[1] = 0.f; ticket[0] = 0u; }
  }
}

// ---------------- K2: symmetric GEMM + row/col mining, ONE-ROUND grid ---------
// Round-quantization model (fits R3/R9/R10/R11): makespan = ceil(NBLK/1024
// resident slots) x T_block. R9's 1056 blocks = 2 rounds; this re-tiling hits
// 1024 exactly -> 1 round. Off-diag blocks (992) identical to R9. The 32 diag
// blocks cover their 256-square with triangular js: wave w runs adjacent-
// subtile pairs (2w,2w+1) from js=2w and (14-2w,15-2w) from js=14-2w ->
// uniform 18 js-steps vs 16 off-diag (1.125x). Col-mine (enabled everywhere)
// picks up the j<i side in diag blocks; self/duplicate coverage is idempotent.
// Wave 0 of each diag block touches all 16 js -> every cposk/cnegk slot is
// written (no NaN-flush hazard). All other structure = R13 (session best).
__global__ __launch_bounds__(256)
__attribute__((amdgpu_waves_per_eu(4, 4)))
void k_mine(
    const unsigned short* __restrict__ xb, const float* __restrict__ sq,
    const int* __restrict__ lab, unsigned* __restrict__ posw, unsigned* __restrict__ negw) {
  __shared__ unsigned cposk[256], cnegk[256];

  const int t = threadIdx.x;
  const int w = t >> 6;
  const int lane = t & 63;
  const int col = lane & 15;   // MFMA m/n selector
  const int quad = lane >> 4;  // MFMA k-group / C row group

  int bj, tile0, js0, tile1, js1, npass;
  {
    const int T = blockIdx.x;
    if (T < 32) {  // diagonal block for square bj
      bj = T;
      npass = 2;
      tile0 = bj * 16 + 2 * w;        js0 = 2 * w;
      tile1 = bj * 16 + 14 - 2 * w;   js1 = 14 - 2 * w;
    } else {       // off-diagonal: decode T-32 -> (bi, bj), offset bj*(bj-1)
      const int Tp = T - 32;
      int b = (int)((1.0f + sqrtf((float)(4 * Tp + 1))) * 0.5f);
      while (b * (b - 1) > Tp) --b;
      while (b * (b + 1) <= Tp) ++b;
      bj = b;
      const int bi = Tp - b * (b - 1);  // in [0, 2bj): strictly above diagonal
      npass = 1;
      tile0 = bi * 8 + 2 * w;  js0 = 0;
      tile1 = 0;               js1 = 0;  // unused
    }
  }
  const int jbase = bj * 256;

  cposk[t] = 0u;
  cnegk[t] = 0xFFFFFFFFu;
  __syncthreads();

  const float* sqp = sq + jbase + col;
  const int* labp = lab + jbase + col;
  const unsigned short* gb = xb + FRAG_OFF(jbase >> 4, 0, lane);

#define LOADB(S, js_) do {                                        \
    const unsigned short* g = gb + (size_t)(js_) * 2048;          \
    b0##S = *(const bf16x8*)(g);                                  \
    b1##S = *(const bf16x8*)(g + 512);                            \
    b2##S = *(const bf16x8*)(g + 1024);                           \
    b3##S = *(const bf16x8*)(g + 1536);                           \
    sqj##S = sqp[(js_) * 16];                                     \
    labj##S = labp[(js_) * 16];                                   \
  } while (0)

#define COMPUTE(S, js_) do {                                                   \
    f32x4 acc0 = {0.f, 0.f, 0.f, 0.f}, acc1 = {0.f, 0.f, 0.f, 0.f};           \
    acc0 = __builtin_amdgcn_mfma_f32_16x16x32_bf16(a[0][0], b0##S, acc0, 0, 0, 0); \
    acc1 = __builtin_amdgcn_mfma_f32_16x16x32_bf16(a[1][0], b0##S, acc1, 0, 0, 0); \
    acc0 = __builtin_amdgcn_mfma_f32_16x16x32_bf16(a[0][1], b1##S, acc0, 0, 0, 0); \
    acc1 = __builtin_amdgcn_mfma_f32_16x16x32_bf16(a[1][1], b1##S, acc1, 0, 0, 0); \
    acc0 = __builtin_amdgcn_mfma_f32_16x16x32_bf16(a[0][2], b2##S, acc0, 0, 0, 0); \
    acc1 = __builtin_amdgcn_mfma_f32_16x16x32_bf16(a[1][2], b2##S, acc1, 0, 0, 0); \
    acc0 = __builtin_amdgcn_mfma_f32_16x16x32_bf16(a[0][3], b3##S, acc0, 0, 0, 0); \
    acc1 = __builtin_amdgcn_mfma_f32_16x16x32_bf16(a[1][3], b3##S, acc1, 0, 0, 0); \
    float cp = -FLT_BIG, cn = FLT_BIG;                                         \
    _Pragma("unroll")                                                          \
    for (int r = 0; r < 4; ++r) {                                              \
      const float m0 = fmaf(-2.f, acc0[r], sqj##S);                            \
      const float m1 = fmaf(-2.f, acc1[r], sqj##S);                            \
      const bool s0 = (labi[0][r] == labj##S);                                 \
      const bool s1 = (labi[1][r] == labj##S);                                 \
      pos[0][r] = fmaxf(pos[0][r], s0 ? m0 : -FLT_BIG);                        \
      neg[0][r] = fminf(neg[0][r], s0 ? FLT_BIG : m0);                         \
      pos[1][r] = fmaxf(pos[1][r], s1 ? m1 : -FLT_BIG);                        \
      neg[1][r] = fminf(neg[1][r], s1 ? FLT_BIG : m1);                         \
      const float mc0 = fmaf(-2.f, acc0[r], sqi[0][r]);                        \
      const float mc1 = fmaf(-2.f, acc1[r], sqi[1][r]);                        \
      cp = fmaxf(cp, s0 ? mc0 : -FLT_BIG);                                     \
      cn = fminf(cn, s0 ? FLT_BIG : mc0);                                      \
      cp = fmaxf(cp, s1 ? mc1 : -FLT_BIG);                                     \
      cn = fminf(cn, s1 ? FLT_BIG : mc1);                                      \
    }                                                                          \
    cp = fmaxf(cp, __shfl_xor(cp, 16, 64));                                    \
    cp = fmaxf(cp, __shfl_xor(cp, 32, 64));                                    \
    cn = fminf(cn, __shfl_xor(cn, 16, 64));                                    \
    cn = fminf(cn, __shfl_xor(cn, 32, 64));                                    \
    if (quad == 0) {                                                           \
      atomicMax(&cposk[(js_) * 16 + col], fkey(cp));                           \
      atomicMin(&cnegk[(js_) * 16 + col], fkey(cn));                           \
    }                                                                          \
  } while (0)

#pragma unroll 1
  for (int p = 0; p < npass; ++p) {
    const int tA = (p == 0) ? tile0 : tile1;
    const int s = (p == 0) ? js0 : js1;  // even, in [0,14]

    // A fragments for adjacent subtile pair (tA, tA+1)
    bf16x8 a[2][4];
#pragma unroll
    for (int is = 0; is < 2; ++is)
#pragma unroll
      for (int k = 0; k < 4; ++k)
        a[is][k] = *(const bf16x8*)(xb + FRAG_OFF(tA + is, k, lane));

    int labi[2][4];
    float sqi[2][4];
#pragma unroll
    for (int is = 0; is < 2; ++is)
#pragma unroll
      for (int r = 0; r < 4; ++r) {
        const int i = (tA + is) * 16 + quad * 4 + r;
        labi[is][r] = lab[i];
        sqi[is][r] = sq[i];
      }

    float pos[2][4], neg[2][4];
#pragma unroll
    for (int is = 0; is < 2; ++is)
#pragma unroll
      for (int r = 0; r < 4; ++r) { pos[is][r] = -FLT_BIG; neg[is][r] = FLT_BIG; }

    bf16x8 b0A, b1A, b2A, b3A, b0B, b1B, b2B, b3B;
    float sqjA, sqjB;
    int labjA, labjB;

    // depth-2 pipeline (R3-proven), dynamic even start s: A=js, B=js+1.
    LOADB(A, s);
#pragma unroll 1
    for (int js = s; js < 14; js += 2) {
      LOADB(B, js + 1);
      COMPUTE(A, js);
      LOADB(A, js + 2);
      COMPUTE(B, js + 1);
    }
    LOADB(B, 15);
    COMPUTE(A, 14);
    COMPUTE(B, 15);

    // row flush: reduce the 16 cols sharing each i-row, add sq_i, atomics
#pragma unroll
    for (int is = 0; is < 2; ++is)
#pragma unroll
      for (int r = 0; r < 4; ++r) {
        float p2 = pos[is][r], n2 = neg[is][r];
#pragma unroll
        for (int off = 1; off < 16; off <<= 1) {
          p2 = fmaxf(p2, __shfl_xor(p2, off, 64));
          n2 = fminf(n2, __shfl_xor(n2, off, 64));
        }
        if (col == 0) {
          const int i = (tA + is) * 16 + quad * 4 + r;
          atomicMax(posw + i, __float_as_uint(fmaxf(sqi[is][r] + p2, 0.f)));
          atomicMin(negw + i, __float_as_uint(fmaxf(sqi[is][r] + n2, 0.f)));
        }
      }
  }

#undef LOADB
#undef COMPUTE

  // col flush: one col per thread (all blocks; every slot touched).
  __syncthreads();
  {
    const int j = jbase + t;
    const float cpv = fkey_inv(cposk[t]);
    const float cnv = fkey_inv(cnegk[t]);
    const float sqj = sq[j];
    atomicMax(posw + j, __float_as_uint(fmaxf(sqj + cpv, 0.f)));
    atomicMin(negw + j, __float_as_uint(fmaxf(sqj + cnv, 0.f)));
  }
}

// ---------------- K3: per-row loss + global reduce + finalize (ticketed) -----
__global__ void k_tail(const unsigned* __restrict__ posw, const unsigned* __restrict__ negw,
                       const int* __restrict__ lab, const unsigned* __restrict__ hist,
                       float* __restrict__ acc, unsigned* __restrict__ ticket,
                       float* __restrict__ out) {
  __shared__ float ls[4], cs[4];
  const int t = threadIdx.x;
  const int i = blockIdx.x * 256 + t;
  const float pd2 = __uint_as_float(posw[i]);
  const float nd2 = __uint_as_float(negw[i]);
  const unsigned cnt = hist[lab[i] & 7];
  const bool valid = (cnt >= 2u) && (cnt < (unsigned)N);
  float loss = 0.f, c = 0.f;
  if (valid) {
    loss = fmaxf(sqrtf(pd2) - sqrtf(fminf(nd2, FLT_BIG)) + MARGIN, 0.f);
    c = 1.f;
  }
#pragma unroll
  for (int off = 1; off < 64; off <<= 1) {
    loss += __shfl_xor(loss, off, 64);
    c += __shfl_xor(c, off, 64);
  }
  const int wv = t >> 6;
  if ((t & 63) == 0) { ls[wv] = loss; cs[wv] = c; }
  __syncthreads();
  if (t == 0) {
    atomicAdd(acc + 0, ls[0] + ls[1] + ls[2] + ls[3]);
    atomicAdd(acc + 1, cs[0] + cs[1] + cs[2] + cs[3]);
    __threadfence();
    const unsigned tk = atomicAdd(ticket, 1u);
    if (tk == 31u) {  // last block: partials fenced-in; read via atomics (coherent)
      const float lsum = atomicAdd(acc + 0, 0.f);
      const float csum = atomicAdd(acc + 1, 0.f);
      out[0] = lsum / fmaxf(csum, 1.f);
    }
  }
}

extern "C" void kernel_launch(void* const* d_in, const int* in_sizes, int n_in,
                              void* d_out, int out_size, void* d_ws, size_t ws_size,
                              hipStream_t stream) {
  const float* x = (const float*)d_in[0];
  const int* lab = (const int*)d_in[1];
  char* ws = (char*)d_ws;
  unsigned short* xb = (unsigned short*)ws;                 // 2 MB bf16 fragment-swizzled
  float* sq = (float*)(ws + (size_t)N * D * 2);             // 32 KB
  unsigned* posw = (unsigned*)((char*)sq + (size_t)N * 4);  // 32 KB
  unsigned* negw = posw + N;                                // 32 KB
  unsigned* hist = negw + N;                                // 32 B
  unsigned* ticket = hist + 8;                              // 4 B
  float* acc = (float*)(ticket + 1);                        // 8 B
  float* out = (float*)d_out;

  hipLaunchKernelGGL(k_prep, dim3(512), dim3(256), 0, stream, x, lab, xb, sq,
                     posw, negw, hist, acc, ticket);
  hipLaunchKernelGGL(k_mine, dim3(NBLK), dim3(256), 0, stream, xb, sq, lab, posw, negw);
  hipLaunchKernelGGL(k_tail, dim3(32), dim3(256), 0, stream, posw, negw, lab, hist,
                     acc, ticket, out);
}

// Round 15
// 96.337 us; speedup vs baseline: 1.1402x; 1.1402x over previous
//
#include <hip/hip_runtime.h>

#define N 8192
#define D 128
#define MARGIN 0.5f
#define FLT_BIG 3.402823466e+38f
// Upper-triangle tiling: 128-row i-tiles x 256-col j-tiles.
// For each j-tile bj (32), i-tiles bi in [0, 2*bj+2) -> sum = 1056 blocks.
#define NBLK 1056

typedef __bf16 bf16x8 __attribute__((ext_vector_type(8)));
typedef float f32x4 __attribute__((ext_vector_type(4)));
typedef unsigned short u16x8 __attribute__((ext_vector_type(8)));

__device__ __forceinline__ unsigned short f2bf_rne(float f) {
  unsigned u = __float_as_uint(f);
  u += 0x7FFFu + ((u >> 16) & 1u);  // round-to-nearest-even (inputs finite)
  return (unsigned short)(u >> 16);
}

// order-preserving float<->uint keys (R1/R9-verified)
__device__ __forceinline__ unsigned fkey(float f) {
  unsigned u = __float_as_uint(f);
  return ((int)u < 0) ? ~u : (u | 0x80000000u);
}
__device__ __forceinline__ float fkey_inv(unsigned k) {
  unsigned u = ((int)k < 0) ? (k & 0x7FFFFFFFu) : ~k;
  return __uint_as_float(u);
}

// xb layout: MFMA-fragment-major. frag[tile][k][lane][8] ushorts, where
// tile = row>>4, lane = quad*16 + (row&15), chunk (4k+quad) = row bytes
// [k*64 + quad*16 .. +16). A and B fragments of the Gram matmul share this
// exact formula, so every fragment load is base + lane*16B (fully coalesced).
#define FRAG_OFF(tile, k, lane) ((size_t)(tile) * 2048 + (size_t)(k) * 512 + (size_t)(lane) * 8)

// ---------------- K1: fp32->bf16 fragment-swizzle + row norms + init ----------
// grid 512 x 256: thread = (row, chunk c): 16 rows/block, 16 chunks/row.
__global__ void k_prep(const float* __restrict__ x, const int* __restrict__ lab,
                       unsigned short* __restrict__ xb, float* __restrict__ sq,
                       unsigned* __restrict__ posw, unsigned* __restrict__ negw,
                       unsigned* __restrict__ hist, float* __restrict__ acc,
                       unsigned* __restrict__ ticket) {
  const int t = threadIdx.x;
  const int row = blockIdx.x * 16 + (t >> 4);
  const int c = t & 15;
  const float4 v0 = ((const float4*)x)[row * 32 + c * 2];
  const float4 v1 = ((const float4*)x)[row * 32 + c * 2 + 1];
  u16x8 o;
  o[0] = f2bf_rne(v0.x); o[1] = f2bf_rne(v0.y);
  o[2] = f2bf_rne(v0.z); o[3] = f2bf_rne(v0.w);
  o[4] = f2bf_rne(v1.x); o[5] = f2bf_rne(v1.y);
  o[6] = f2bf_rne(v1.z); o[7] = f2bf_rne(v1.w);
  // chunk c -> k = c>>2, quad = c&3; lane = quad*16 + (row&15)
  *(u16x8*)(xb + FRAG_OFF(row >> 4, c >> 2, ((c & 3) * 16) + (row & 15))) = o;
  float s = v0.x * v0.x + v0.y * v0.y + v0.z * v0.z + v0.w * v0.w +
            v1.x * v1.x + v1.y * v1.y + v1.z * v1.z + v1.w * v1.w;
#pragma unroll
  for (int off = 1; off < 16; off <<= 1) s += __shfl_xor(s, off, 64);
  if (c == 0) {
    sq[row] = s;
    posw[row] = 0u;           // max(d2) accumulator
    negw[row] = 0x7F800000u;  // min(d2) accumulator = +inf
  }

  if (blockIdx.x == 0) {  // label histogram
    __shared__ unsigned h[8];
    if (t < 8) h[t] = 0u;
    __syncthreads();
    unsigned long long cA = 0ull, cB = 0ull;  // 4x16-bit packed counters each
#pragma unroll
    for (int it = 0; it < 32; ++it) {
      const int l = lab[t + it * 256] & 7;
      if (l < 4) cA += 1ull << (l * 16);
      else       cB += 1ull << ((l - 4) * 16);
    }
#pragma unroll
    for (int off = 1; off < 64; off <<= 1) {
      cA += __shfl_xor(cA, off, 64);
      cB += __shfl_xor(cB, off, 64);
    }
    if ((t & 63) == 0) {
#pragma unroll
      for (int q = 0; q < 4; ++q) {
        atomicAdd(&h[q],     (unsigned)((cA >> (q * 16)) & 0xFFFFu));
        atomicAdd(&h[4 + q], (unsigned)((cB >> (q * 16)) & 0xFFFFu));
      }
    }
    __syncthreads();
    if (t < 8) hist[t] = h[t];
    if (t == 0) { acc[0] = 0.f; acc[1] = 0.f; ticket[0] = 0u; }
  }
}

// ---------------- K2: symmetric GEMM + row/col mining (triangle, NO fences) ---
// SESSION-FINAL STRUCTURE (R9/R13, 97.8-98.4us total). Measured alternatives:
// depth-3 pipeline spills (R5); LDS staging serializes on barrier vmcnt drain
// (R4); per-block __threadfence costs ~70us/1000 blocks (R1/R4/R6, confirmed
// by R12's fence removal: 183->109); fused ticketed tail perturbs regalloc to
// 64 VGPR + spill even fenceless (R12); occupancy redesigns at 16-rows/wave
// lose to per-element overhead (R10) / allocator drops prefetch (R11);
// blockIdx swizzles neutral (R7); MFMA/MINE cross-tile overlap neutral (R8);
// 1024-block one-round re-tiling regresses on diag-straggler + dynamic-start
// pipeline (R14: 110us).
// Diag-parent blocks (bi>>1==bj) mine rows only; col-mine there would only
// double-count + add the self-term.
__global__ __launch_bounds__(256)
__attribute__((amdgpu_waves_per_eu(4, 4)))
void k_mine(
    const unsigned short* __restrict__ xb, const float* __restrict__ sq,
    const int* __restrict__ lab, unsigned* __restrict__ posw, unsigned* __restrict__ negw) {
  __shared__ unsigned cposk[256], cnegk[256];

  const int t = threadIdx.x;
  const int w = t >> 6;
  const int lane = t & 63;
  const int col = lane & 15;   // MFMA m/n selector
  const int quad = lane >> 4;  // MFMA k-group / C row group

  // decode block -> (bi, bj): offset(bj) = bj*(bj+1)
  int bj, bi;
  {
    const int T = blockIdx.x;
    int b = (int)((sqrtf((float)(4 * T + 1)) - 1.0f) * 0.5f);
    while (b * (b + 1) > T) --b;
    while ((b + 1) * (b + 2) <= T) ++b;
    bj = b;
    bi = T - b * (b + 1);
  }
  const bool diag = ((bi >> 1) == bj);
  const int i0 = bi * 128 + w * 32;
  const int jbase = bj * 256;

  cposk[t] = 0u;
  cnegk[t] = 0xFFFFFFFFu;
  __syncthreads();

  // A fragments resident: 2 i-subtiles x 4 k-steps (coalesced loads)
  bf16x8 a[2][4];
#pragma unroll
  for (int is = 0; is < 2; ++is)
#pragma unroll
    for (int k = 0; k < 4; ++k)
      a[is][k] = *(const bf16x8*)(xb + FRAG_OFF((i0 >> 4) + is, k, lane));

  int labi[2][4];
  float sqi[2][4];
#pragma unroll
  for (int is = 0; is < 2; ++is)
#pragma unroll
    for (int r = 0; r < 4; ++r) {
      const int i = i0 + is * 16 + quad * 4 + r;
      labi[is][r] = lab[i];
      sqi[is][r] = sq[i];
    }

  float pos[2][4], neg[2][4];
#pragma unroll
  for (int is = 0; is < 2; ++is)
#pragma unroll
    for (int r = 0; r < 4; ++r) { pos[is][r] = -FLT_BIG; neg[is][r] = FLT_BIG; }

  const float* sqp = sq + jbase + col;
  const int* labp = lab + jbase + col;
  const unsigned short* gb = xb + FRAG_OFF(jbase >> 4, 0, lane);

  bf16x8 b0A, b1A, b2A, b3A, b0B, b1B, b2B, b3B;
  float sqjA, sqjB;
  int labjA, labjB;

#define LOADB(S, js_) do {                                        \
    const unsigned short* g = gb + (size_t)(js_) * 2048;          \
    b0##S = *(const bf16x8*)(g);                                  \
    b1##S = *(const bf16x8*)(g + 512);                            \
    b2##S = *(const bf16x8*)(g + 1024);                           \
    b3##S = *(const bf16x8*)(g + 1536);                           \
    sqj##S = sqp[(js_) * 16];                                     \
    labj##S = labp[(js_) * 16];                                   \
  } while (0)

#define COMPUTE(S, js_) do {                                                   \
    f32x4 acc0 = {0.f, 0.f, 0.f, 0.f}, acc1 = {0.f, 0.f, 0.f, 0.f};           \
    acc0 = __builtin_amdgcn_mfma_f32_16x16x32_bf16(a[0][0], b0##S, acc0, 0, 0, 0); \
    acc1 = __builtin_amdgcn_mfma_f32_16x16x32_bf16(a[1][0], b0##S, acc1, 0, 0, 0); \
    acc0 = __builtin_amdgcn_mfma_f32_16x16x32_bf16(a[0][1], b1##S, acc0, 0, 0, 0); \
    acc1 = __builtin_amdgcn_mfma_f32_16x16x32_bf16(a[1][1], b1##S, acc1, 0, 0, 0); \
    acc0 = __builtin_amdgcn_mfma_f32_16x16x32_bf16(a[0][2], b2##S, acc0, 0, 0, 0); \
    acc1 = __builtin_amdgcn_mfma_f32_16x16x32_bf16(a[1][2], b2##S, acc1, 0, 0, 0); \
    acc0 = __builtin_amdgcn_mfma_f32_16x16x32_bf16(a[0][3], b3##S, acc0, 0, 0, 0); \
    acc1 = __builtin_amdgcn_mfma_f32_16x16x32_bf16(a[1][3], b3##S, acc1, 0, 0, 0); \
    float cp = -FLT_BIG, cn = FLT_BIG;                                         \
    _Pragma("unroll")                                                          \
    for (int r = 0; r < 4; ++r) {                                              \
      const float m0 = fmaf(-2.f, acc0[r], sqj##S);                            \
      const float m1 = fmaf(-2.f, acc1[r], sqj##S);                            \
      const bool s0 = (labi[0][r] == labj##S);                                 \
      const bool s1 = (labi[1][r] == labj##S);                                 \
      pos[0][r] = fmaxf(pos[0][r], s0 ? m0 : -FLT_BIG);                        \
      neg[0][r] = fminf(neg[0][r], s0 ? FLT_BIG : m0);                         \
      pos[1][r] = fmaxf(pos[1][r], s1 ? m1 : -FLT_BIG);                        \
      neg[1][r] = fminf(neg[1][r], s1 ? FLT_BIG : m1);                         \
      if (!diag) {                                                             \
        const float mc0 = fmaf(-2.f, acc0[r], sqi[0][r]);                      \
        const float mc1 = fmaf(-2.f, acc1[r], sqi[1][r]);                      \
        cp = fmaxf(cp, s0 ? mc0 : -FLT_BIG);                                   \
        cn = fminf(cn, s0 ? FLT_BIG : mc0);                                    \
        cp = fmaxf(cp, s1 ? mc1 : -FLT_BIG);                                   \
        cn = fminf(cn, s1 ? FLT_BIG : mc1);                                    \
      }                                                                        \
    }                                                                          \
    if (!diag) {                                                               \
      cp = fmaxf(cp, __shfl_xor(cp, 16, 64));                                  \
      cp = fmaxf(cp, __shfl_xor(cp, 32, 64));                                  \
      cn = fminf(cn, __shfl_xor(cn, 16, 64));                                  \
      cn = fminf(cn, __shfl_xor(cn, 32, 64));                                  \
      if (quad == 0) {                                                         \
        atomicMax(&cposk[(js_) * 16 + col], fkey(cp));                         \
        atomicMin(&cnegk[(js_) * 16 + col], fkey(cn));                         \
      }                                                                        \
    }                                                                          \
  } while (0)

  // depth-2 pipeline (R3-proven): A holds js, B holds js+1.
  LOADB(A, 0);
#pragma unroll 1
  for (int js = 0; js < 14; js += 2) {
    LOADB(B, js + 1);
    COMPUTE(A, js);
    LOADB(A, js + 2);
    COMPUTE(B, js + 1);
  }
  LOADB(B, 15);
  COMPUTE(A, 14);
  COMPUTE(B, 15);

#undef LOADB
#undef COMPUTE

  // row flush: reduce the 16 cols sharing each i-row, add sq_i, atomics
#pragma unroll
  for (int is = 0; is < 2; ++is)
#pragma unroll
    for (int r = 0; r < 4; ++r) {
      float p = pos[is][r], n = neg[is][r];
#pragma unroll
      for (int off = 1; off < 16; off <<= 1) {
        p = fmaxf(p, __shfl_xor(p, off, 64));
        n = fminf(n, __shfl_xor(n, off, 64));
      }
      if (col == 0) {
        const int i = i0 + is * 16 + quad * 4 + r;
        atomicMax(posw + i, __float_as_uint(fmaxf(sqi[is][r] + p, 0.f)));
        atomicMin(negw + i, __float_as_uint(fmaxf(sqi[is][r] + n, 0.f)));
      }
    }

  // col flush: one col per thread (off-diag blocks only; block-uniform branch)
  if (!diag) {
    __syncthreads();
    const int j = jbase + t;
    const float cpv = fkey_inv(cposk[t]);
    const float cnv = fkey_inv(cnegk[t]);
    const float sqj = sq[j];
    atomicMax(posw + j, __float_as_uint(fmaxf(sqj + cpv, 0.f)));
    atomicMin(negw + j, __float_as_uint(fmaxf(sqj + cnv, 0.f)));
  }
}

// ---------------- K3: per-row loss + global reduce + finalize (ticketed) -----
__global__ void k_tail(const unsigned* __restrict__ posw, const unsigned* __restrict__ negw,
                       const int* __restrict__ lab, const unsigned* __restrict__ hist,
                       float* __restrict__ acc, unsigned* __restrict__ ticket,
                       float* __restrict__ out) {
  __shared__ float ls[4], cs[4];
  const int t = threadIdx.x;
  const int i = blockIdx.x * 256 + t;
  const float pd2 = __uint_as_float(posw[i]);
  const float nd2 = __uint_as_float(negw[i]);
  const unsigned cnt = hist[lab[i] & 7];
  const bool valid = (cnt >= 2u) && (cnt < (unsigned)N);
  float loss = 0.f, c = 0.f;
  if (valid) {
    loss = fmaxf(sqrtf(pd2) - sqrtf(fminf(nd2, FLT_BIG)) + MARGIN, 0.f);
    c = 1.f;
  }
#pragma unroll
  for (int off = 1; off < 64; off <<= 1) {
    loss += __shfl_xor(loss, off, 64);
    c += __shfl_xor(c, off, 64);
  }
  const int wv = t >> 6;
  if ((t & 63) == 0) { ls[wv] = loss; cs[wv] = c; }
  __syncthreads();
  if (t == 0) {
    atomicAdd(acc + 0, ls[0] + ls[1] + ls[2] + ls[3]);
    atomicAdd(acc + 1, cs[0] + cs[1] + cs[2] + cs[3]);
    __threadfence();
    const unsigned tk = atomicAdd(ticket, 1u);
    if (tk == 31u) {  // last block: partials fenced-in; read via atomics (coherent)
      const float lsum = atomicAdd(acc + 0, 0.f);
      const float csum = atomicAdd(acc + 1, 0.f);
      out[0] = lsum / fmaxf(csum, 1.f);
    }
  }
}

extern "C" void kernel_launch(void* const* d_in, const int* in_sizes, int n_in,
                              void* d_out, int out_size, void* d_ws, size_t ws_size,
                              hipStream_t stream) {
  const float* x = (const float*)d_in[0];
  const int* lab = (const int*)d_in[1];
  char* ws = (char*)d_ws;
  unsigned short* xb = (unsigned short*)ws;                 // 2 MB bf16 fragment-swizzled
  float* sq = (float*)(ws + (size_t)N * D * 2);             // 32 KB
  unsigned* posw = (unsigned*)((char*)sq + (size_t)N * 4);  // 32 KB
  unsigned* negw = posw + N;                                // 32 KB
  unsigned* hist = negw + N;                                // 32 B
  unsigned* ticket = hist + 8;                              // 4 B
  float* acc = (float*)(ticket + 1);                        // 8 B
  float* out = (float*)d_out;

  hipLaunchKernelGGL(k_prep, dim3(512), dim3(256), 0, stream, x, lab, xb, sq,
                     posw, negw, hist, acc, ticket);
  hipLaunchKernelGGL(k_mine, dim3(NBLK), dim3(256), 0, stream, xb, sq, lab, posw, negw);
  hipLaunchKernelGGL(k_tail, dim3(32), dim3(256), 0, stream, posw, negw, lab, hist,
                     acc, ticket, out);
}